// Round 7
// baseline (547.205 us; speedup 1.0000x reference)
//
#include <hip/hip_runtime.h>
#include <hip/hip_bf16.h>
#include <math.h>

typedef __attribute__((ext_vector_type(8))) short short8;
typedef __attribute__((ext_vector_type(4))) float floatx4;

__device__ __forceinline__ unsigned short bfb(float x) {
    union { __hip_bfloat16 h; unsigned short u; } c;
    c.h = __float2bfloat16(x);
    return c.u;
}
__device__ __forceinline__ float bf2f(unsigned short u) {
    union { unsigned int i; float f; } c;
    c.i = ((unsigned int)u) << 16;
    return c.f;
}
// accumulate the two bf16 halves of a dword into two f32 accumulators
__device__ __forceinline__ void acc2(float& lo, float& hi, unsigned d) {
    union { unsigned u; float f; } a, b;
    a.u = d << 16;
    b.u = d & 0xffff0000u;
    lo += a.f; hi += b.f;
}
// packed unsigned 16-bit max (gfx9 VOP3P, inherited on CDNA4)
__device__ __forceinline__ unsigned pkmaxu16(unsigned a, unsigned b) {
    unsigned d;
    asm("v_pk_max_u16 %0, %1, %2" : "=v"(d) : "v"(a), "v"(b));
    return d;
}

#define SLABC 5120          // slab capacity per 256-node bucket (Poisson(4096)+16 sigma)
#define PCHUNK 8192

// ---------------- slab-bucket CSR build (2 kernels, no scan) ----------------

__global__ __launch_bounds__(256) void k_partA(const int* __restrict__ src, const int* __restrict__ dst,
                                               int* __restrict__ bcur, unsigned* __restrict__ ebuf, int E) {
    __shared__ int h[512];
    __shared__ int base[512];
    int t = threadIdx.x;
    for (int i = t; i < 512; i += 256) h[i] = 0;
    __syncthreads();
    int start = blockIdx.x * PCHUNK;
    int end = start + PCHUNK < E ? start + PCHUNK : E;
    for (int i = start + t; i < end; i += 256) atomicAdd(&h[dst[i] >> 8], 1);
    __syncthreads();
    for (int i = t; i < 512; i += 256) {
        int c = h[i];
        base[i] = c ? atomicAdd(&bcur[i], c) : 0;
        h[i] = 0;
    }
    __syncthreads();
    for (int i = start + t; i < end; i += 256) {
        int d = dst[i];
        int b = d >> 8;
        int r = atomicAdd(&h[b], 1);
        ebuf[b * SLABC + base[b] + r] = ((unsigned)src[i] << 8) | (unsigned)(d & 255);
    }
}

// per-bucket: node degrees, local scan, row_be/dinv/dsq, csr scatter, feat->bf16 prescale
__global__ __launch_bounds__(256) void k_finish(const unsigned* __restrict__ ebuf, const int* __restrict__ bcur,
                                                int2* __restrict__ row_be, float* __restrict__ dinv,
                                                float* __restrict__ dsq, int* __restrict__ csr,
                                                const float* __restrict__ feat, unsigned short* __restrict__ hd,
                                                int N) {
    __shared__ int h[256];
    __shared__ int sc[256];
    __shared__ int cur[256];
    int b = blockIdx.x, t = threadIdx.x;
    h[t] = 0;
    __syncthreads();
    int beg = b * SLABC, end = beg + bcur[b];
    for (int e = beg + t; e < end; e += 256) atomicAdd(&h[ebuf[e] & 255], 1);
    __syncthreads();
    int v = h[t];
    sc[t] = v;
    __syncthreads();
    for (int off = 1; off < 256; off <<= 1) {
        int x = (t >= off) ? sc[t - off] : 0;
        __syncthreads();
        sc[t] += x;
        __syncthreads();
    }
    int node = (b << 8) + t;
    int excl = beg + sc[t] - v;
    if (node < N) {
        row_be[node] = make_int2(excl, excl + v);
        float dg = (float)(v > 1 ? v : 1);
        float dv = rsqrtf(dg);
        dinv[node] = dv;
        dsq[node] = sqrtf(dg);
        const float* f = &feat[(size_t)node * 16];
#pragma unroll
        for (int k = 0; k < 16; k += 4) {
            float4 x = *(const float4*)&f[k];
            ushort4 u = { bfb(x.x * dv), bfb(x.y * dv), bfb(x.z * dv), bfb(x.w * dv) };
            *(ushort4*)&hd[(size_t)node * 16 + k] = u;
        }
    }
    cur[t] = excl;
    __syncthreads();
    for (int e = beg + t; e < end; e += 256) {
        unsigned ed = ebuf[e];
        int pos = atomicAdd(&cur[ed & 255], 1);
        csr[pos] = (int)(ed >> 8);
    }
}

// ---------------- 16-dim X1 aggregation (padded branch-free; bf16 X1 + scaled xd) ----------------

__global__ __launch_bounds__(256) void k_aggr16(const unsigned short* __restrict__ Xd,
                                                const float* __restrict__ dinv,
                                                const int2* __restrict__ row_be, const int* __restrict__ csr,
                                                unsigned short* __restrict__ outb, unsigned short* __restrict__ outd,
                                                int zoff, int N) {
    int node = blockIdx.x * 4 + (threadIdx.x >> 6);
    if (node >= N) return;
    int lane = threadIdx.x & 63;
    int g = lane >> 2;                  // 16 edge groups
    int co = (lane & 3) * 8;            // byte offset of this lane's 4 cols
    int2 be = row_be[node];
    int beg = be.x, end = be.y;
    int deg = end - beg;
    int myOff = (lane < deg) ? (csr[beg + lane] << 5) : zoff;   // 32B rows; pad -> zero page
    const char* base = (const char*)Xd + co;
    float a0 = 0.f, a1 = 0.f, a2 = 0.f, a3 = 0.f;
    {
        int o0 = __shfl(myOff, g);
        int o1 = __shfl(myOff, 16 + g);
        ushort4 x0 = *(const ushort4*)(base + o0);
        ushort4 x1 = *(const ushort4*)(base + o1);
        a0 += bf2f(x0.x); a1 += bf2f(x0.y); a2 += bf2f(x0.z); a3 += bf2f(x0.w);
        a0 += bf2f(x1.x); a1 += bf2f(x1.y); a2 += bf2f(x1.z); a3 += bf2f(x1.w);
    }
    if (deg > 32) {
        int dmain = deg < 64 ? deg : 64;
        for (int j = 32; j < dmain; j += 16) {
            int o = __shfl(myOff, j + g);
            ushort4 x = *(const ushort4*)(base + o);
            a0 += bf2f(x.x); a1 += bf2f(x.y); a2 += bf2f(x.z); a3 += bf2f(x.w);
        }
        for (int e = beg + 64; e < end; e += 16) {
            int idx = e + g;
            int s = csr[idx < end ? idx : end - 1];
            ushort4 x = *(const ushort4*)(base + (s << 5));
            if (idx < end) {
                a0 += bf2f(x.x); a1 += bf2f(x.y); a2 += bf2f(x.z); a3 += bf2f(x.w);
            }
        }
    }
    a0 += __shfl_xor(a0, 4); a0 += __shfl_xor(a0, 8); a0 += __shfl_xor(a0, 16); a0 += __shfl_xor(a0, 32);
    a1 += __shfl_xor(a1, 4); a1 += __shfl_xor(a1, 8); a1 += __shfl_xor(a1, 16); a1 += __shfl_xor(a1, 32);
    a2 += __shfl_xor(a2, 4); a2 += __shfl_xor(a2, 8); a2 += __shfl_xor(a2, 16); a2 += __shfl_xor(a2, 32);
    a3 += __shfl_xor(a3, 4); a3 += __shfl_xor(a3, 8); a3 += __shfl_xor(a3, 16); a3 += __shfl_xor(a3, 32);
    if (g == 0) {
        int c4 = (lane & 3) * 4;
        float dn = dinv[node];
        float v0 = -dn * a0, v1 = -dn * a1, v2 = -dn * a2, v3 = -dn * a3;   // X1 = -aggr(X0)
        ushort4 ub = { bfb(v0), bfb(v1), bfb(v2), bfb(v3) };
        *(ushort4*)&outb[(size_t)node * 16 + c4] = ub;
        ushort4 u = { bfb(v0 * dn), bfb(v1 * dn), bfb(v2 * dn), bfb(v3 * dn) };
        *(ushort4*)&outd[(size_t)node * 16 + c4] = u;
    }
}

// ---------------- 64-dim X1 aggregation (writes only dinv-scaled xd; cheb rescales) ----------------

__global__ __launch_bounds__(256) void k_aggr64(const unsigned short* __restrict__ Xd,
                                                const float* __restrict__ dinv,
                                                const int2* __restrict__ row_be, const int* __restrict__ csr,
                                                unsigned short* __restrict__ outd, int zoff, int N) {
    int node = blockIdx.x * 4 + (threadIdx.x >> 6);
    if (node >= N) return;
    int lane = threadIdx.x & 63;
    int g = lane >> 3;                  // 8 edge groups
    int co = (lane & 7) * 16;           // byte offset of this lane's 8 cols
    int2 be = row_be[node];
    int beg = be.x, end = be.y;
    int deg = end - beg;
    int myOff = (lane < deg) ? (csr[beg + lane] << 7) : zoff;   // 128B rows; pad -> zero page
    const char* base = (const char*)Xd + co;
    float a0 = 0.f, a1 = 0.f, a2 = 0.f, a3 = 0.f, a4 = 0.f, a5 = 0.f, a6 = 0.f, a7 = 0.f;
    {
        int o0 = __shfl(myOff, g);
        int o1 = __shfl(myOff, 8 + g);
        int o2 = __shfl(myOff, 16 + g);
        int o3 = __shfl(myOff, 24 + g);
        uint4 x0 = *(const uint4*)(base + o0);
        uint4 x1 = *(const uint4*)(base + o1);
        uint4 x2 = *(const uint4*)(base + o2);
        uint4 x3 = *(const uint4*)(base + o3);
        acc2(a0, a1, x0.x); acc2(a2, a3, x0.y); acc2(a4, a5, x0.z); acc2(a6, a7, x0.w);
        acc2(a0, a1, x1.x); acc2(a2, a3, x1.y); acc2(a4, a5, x1.z); acc2(a6, a7, x1.w);
        acc2(a0, a1, x2.x); acc2(a2, a3, x2.y); acc2(a4, a5, x2.z); acc2(a6, a7, x2.w);
        acc2(a0, a1, x3.x); acc2(a2, a3, x3.y); acc2(a4, a5, x3.z); acc2(a6, a7, x3.w);
    }
    if (deg > 32) {
        int dmain = deg < 64 ? deg : 64;
        for (int j = 32; j < dmain; j += 8) {
            int o = __shfl(myOff, j + g);
            uint4 x = *(const uint4*)(base + o);
            acc2(a0, a1, x.x); acc2(a2, a3, x.y); acc2(a4, a5, x.z); acc2(a6, a7, x.w);
        }
        for (int e = beg + 64; e < end; e += 8) {
            int idx = e + g;
            int s = csr[idx < end ? idx : end - 1];
            uint4 x = *(const uint4*)(base + (s << 7));
            if (idx < end) {
                acc2(a0, a1, x.x); acc2(a2, a3, x.y); acc2(a4, a5, x.z); acc2(a6, a7, x.w);
            }
        }
    }
    a0 += __shfl_xor(a0, 8); a0 += __shfl_xor(a0, 16); a0 += __shfl_xor(a0, 32);
    a1 += __shfl_xor(a1, 8); a1 += __shfl_xor(a1, 16); a1 += __shfl_xor(a1, 32);
    a2 += __shfl_xor(a2, 8); a2 += __shfl_xor(a2, 16); a2 += __shfl_xor(a2, 32);
    a3 += __shfl_xor(a3, 8); a3 += __shfl_xor(a3, 16); a3 += __shfl_xor(a3, 32);
    a4 += __shfl_xor(a4, 8); a4 += __shfl_xor(a4, 16); a4 += __shfl_xor(a4, 32);
    a5 += __shfl_xor(a5, 8); a5 += __shfl_xor(a5, 16); a5 += __shfl_xor(a5, 32);
    a6 += __shfl_xor(a6, 8); a6 += __shfl_xor(a6, 16); a6 += __shfl_xor(a6, 32);
    a7 += __shfl_xor(a7, 8); a7 += __shfl_xor(a7, 16); a7 += __shfl_xor(a7, 32);
    if (g == 0) {                       // lanes 0..7 hold cols lane*8 .. lane*8+7
        float dn = dinv[node];
        float v[8] = { a0, a1, a2, a3, a4, a5, a6, a7 };
        uint4 ud;
        unsigned* pd = (unsigned*)&ud;
#pragma unroll
        for (int i = 0; i < 4; ++i) {
            float lo = -dn * dn * v[2 * i];         // xd = dinv * X1 = -dn^2 * sum
            float hi = -dn * dn * v[2 * i + 1];
            pd[i] = (unsigned)bfb(lo) | ((unsigned)bfb(hi) << 16);
        }
        *(uint4*)((char*)outd + (size_t)node * 128 + co) = ud;
    }
}

// ---------------- fused X2-gather + Cheb MFMA + (EdgeConv e1 | pool) , KDIM=16 ----------------
// X2 = -2*dinv*aggr(xd) - feat, gathered in-block into LDS (xd complete from prior kernel).

__global__ __launch_bounds__(256) void k_cheb16f(const float* __restrict__ feat,
                                                 const unsigned short* __restrict__ X1b,
                                                 const unsigned short* __restrict__ xd,
                                                 const int2* __restrict__ row_be, const int* __restrict__ csr,
                                                 const float* __restrict__ dinv,
                                                 const float* __restrict__ W, const float* __restrict__ bvec,
                                                 const float* __restrict__ Wt, const float* __restrict__ Wp,
                                                 const float* __restrict__ bt, const float* __restrict__ bp,
                                                 unsigned short* __restrict__ md, unsigned short* __restrict__ pbuf,
                                                 int zoff, int N) {
    constexpr int SX = 72;
    __shared__ unsigned short S[13824];     // phase1: Ws 64x72 | Xs2 64x24 ; phase2: Hs 64x72 + W2l 128x72
    unsigned short* Ws = S;
    unsigned short* Xs2 = S + 64 * 72;
    int t = threadIdx.x;
    int wave = t >> 6, lane = t & 63;

    // stage Ws (K-padded to 64)
    for (int idx = t; idx < 3072; idx += 256) {
        int a = idx >> 10;
        int r = idx & 1023;
        int k = r >> 6, n = r & 63;
        Ws[n * SX + a * 16 + k] = bfb(W[idx]);
    }
    for (int idx = t; idx < 1024; idx += 256) {
        int n = idx & 63, k = 48 + (idx >> 6);
        Ws[n * SX + k] = 0;
    }

    // in-block X2 gather: each wave covers 16 rows
    {
        int g = lane >> 2;
        int co = (lane & 3) * 8;
        const char* base = (const char*)xd + co;
        for (int i = 0; i < 16; ++i) {
            int ln = wave * 16 + i;
            int gn = blockIdx.x * 64 + ln; if (gn >= N) gn = N - 1;
            int2 be = row_be[gn];
            int beg = be.x, end = be.y;
            int deg = end - beg;
            int myOff = (lane < deg) ? (csr[beg + lane] << 5) : zoff;
            float a0 = 0.f, a1 = 0.f, a2 = 0.f, a3 = 0.f;
            {
                int o0 = __shfl(myOff, g);
                int o1 = __shfl(myOff, 16 + g);
                ushort4 x0 = *(const ushort4*)(base + o0);
                ushort4 x1 = *(const ushort4*)(base + o1);
                a0 += bf2f(x0.x); a1 += bf2f(x0.y); a2 += bf2f(x0.z); a3 += bf2f(x0.w);
                a0 += bf2f(x1.x); a1 += bf2f(x1.y); a2 += bf2f(x1.z); a3 += bf2f(x1.w);
            }
            if (deg > 32) {
                int dmain = deg < 64 ? deg : 64;
                for (int j = 32; j < dmain; j += 16) {
                    int o = __shfl(myOff, j + g);
                    ushort4 x = *(const ushort4*)(base + o);
                    a0 += bf2f(x.x); a1 += bf2f(x.y); a2 += bf2f(x.z); a3 += bf2f(x.w);
                }
                for (int e = beg + 64; e < end; e += 16) {
                    int idx = e + g;
                    int s = csr[idx < end ? idx : end - 1];
                    ushort4 x = *(const ushort4*)(base + (s << 5));
                    if (idx < end) {
                        a0 += bf2f(x.x); a1 += bf2f(x.y); a2 += bf2f(x.z); a3 += bf2f(x.w);
                    }
                }
            }
            a0 += __shfl_xor(a0, 4); a0 += __shfl_xor(a0, 8); a0 += __shfl_xor(a0, 16); a0 += __shfl_xor(a0, 32);
            a1 += __shfl_xor(a1, 4); a1 += __shfl_xor(a1, 8); a1 += __shfl_xor(a1, 16); a1 += __shfl_xor(a1, 32);
            a2 += __shfl_xor(a2, 4); a2 += __shfl_xor(a2, 8); a2 += __shfl_xor(a2, 16); a2 += __shfl_xor(a2, 32);
            a3 += __shfl_xor(a3, 4); a3 += __shfl_xor(a3, 8); a3 += __shfl_xor(a3, 16); a3 += __shfl_xor(a3, 32);
            if (g == 0) {
                int c4 = (lane & 3) * 4;
                float dn = dinv[gn];
                float4 zv = *(const float4*)&feat[(size_t)gn * 16 + c4];
                float v0 = -2.f * dn * a0 - zv.x;
                float v1 = -2.f * dn * a1 - zv.y;
                float v2 = -2.f * dn * a2 - zv.z;
                float v3 = -2.f * dn * a3 - zv.w;
                ushort4 u = { bfb(v0), bfb(v1), bfb(v2), bfb(v3) };
                *(ushort4*)&Xs2[ln * 24 + c4] = u;
            }
        }
    }
    __syncthreads();

    int fi = lane & 15, quad = lane >> 4;
    int arow = wave * 16 + fi;
    int arow_node = blockIdx.x * 64 + arow;
    int anode = arow_node < N ? arow_node : N - 1;

    floatx4 acc[4];
#pragma unroll
    for (int i = 0; i < 4; ++i) acc[i] = (floatx4){0.f,0.f,0.f,0.f};
#pragma unroll
    for (int ks = 0; ks < 2; ++ks) {
#pragma unroll
        for (int q2 = 0; q2 < 1; ++q2) {}   // (keep structure simple)
        int kidx = ks * 32 + quad * 8;
        int seg = kidx >> 4;
        short8 af;
        if (seg == 0) {
            const float* rp = &feat[(size_t)anode * 16 + (kidx & 15)];
            float4 v0 = *(const float4*)rp;
            float4 v1 = *(const float4*)(rp + 4);
            af = (short8){ (short)bfb(v0.x), (short)bfb(v0.y), (short)bfb(v0.z), (short)bfb(v0.w),
                           (short)bfb(v1.x), (short)bfb(v1.y), (short)bfb(v1.z), (short)bfb(v1.w) };
        } else if (seg == 1) {
            af = *(const short8*)&X1b[(size_t)anode * 16 + (kidx & 15)];
        } else if (seg == 2) {
            af = *(const short8*)&Xs2[arow * 24 + (kidx & 15)];
        } else {
            af = (short8){0,0,0,0,0,0,0,0};
        }
        short8 b0 = *(const short8*)&Ws[(0 * 16 + fi) * SX + kidx];
        short8 b1 = *(const short8*)&Ws[(1 * 16 + fi) * SX + kidx];
        short8 b2 = *(const short8*)&Ws[(2 * 16 + fi) * SX + kidx];
        short8 b3 = *(const short8*)&Ws[(3 * 16 + fi) * SX + kidx];
        acc[0] = __builtin_amdgcn_mfma_f32_16x16x32_bf16(af, b0, acc[0], 0, 0, 0);
        acc[1] = __builtin_amdgcn_mfma_f32_16x16x32_bf16(af, b1, acc[1], 0, 0, 0);
        acc[2] = __builtin_amdgcn_mfma_f32_16x16x32_bf16(af, b2, acc[2], 0, 0, 0);
        acc[3] = __builtin_amdgcn_mfma_f32_16x16x32_bf16(af, b3, acc[3], 0, 0, 0);
    }

    int nbase = blockIdx.x * 64 + wave * 16 + quad * 4;
    float rv[4][4];
#pragma unroll
    for (int nt = 0; nt < 4; ++nt) {
        float bias = bvec[nt * 16 + fi];
#pragma unroll
        for (int reg = 0; reg < 4; ++reg) rv[nt][reg] = fmaxf(acc[nt][reg] + bias, 0.f);
    }

    // e1 phase
    __syncthreads();
    unsigned short* Hs = S;
    unsigned short* W2l = S + 64 * 72;
    int lrow = wave * 16 + quad * 4;
#pragma unroll
    for (int nt = 0; nt < 4; ++nt)
#pragma unroll
        for (int reg = 0; reg < 4; ++reg)
            Hs[(lrow + reg) * 72 + nt * 16 + fi] = bfb(rv[nt][reg]);
    for (int idx = t; idx < 4096; idx += 256) {
        int k = idx >> 6, n = idx & 63;
        float wt = Wt[idx];
        W2l[n * 72 + k] = bfb(wt);
        W2l[(64 + n) * 72 + k] = bfb(wt + Wp[idx]);
    }
    __syncthreads();
    floatx4 ae[8];
#pragma unroll
    for (int i = 0; i < 8; ++i) ae[i] = (floatx4){0.f,0.f,0.f,0.f};
#pragma unroll
    for (int ks = 0; ks < 2; ++ks) {
        short8 af = *(const short8*)&Hs[arow * 72 + ks * 32 + quad * 8];
#pragma unroll
        for (int nt = 0; nt < 8; ++nt) {
            short8 bf = *(const short8*)&W2l[(nt * 16 + fi) * 72 + ks * 32 + quad * 8];
            ae[nt] = __builtin_amdgcn_mfma_f32_16x16x32_bf16(af, bf, ae[nt], 0, 0, 0);
        }
    }
#pragma unroll
    for (int nt = 0; nt < 8; ++nt) {
        int col = nt * 16 + fi;
        if (col < 64) {
#pragma unroll
            for (int reg = 0; reg < 4; ++reg) {
                int node = nbase + reg;
                if (node < N) {
                    unsigned u = (unsigned)bfb(ae[nt][reg]) ^ 0x8000u;
                    unsigned key = (u & 0x8000u) ? (~u & 0xffffu) : (u | 0x8000u);
                    md[(size_t)node * 64 + col] = (unsigned short)key;
                }
            }
        } else {
            int cc = col - 64;
            float bias2 = bt[cc] + bp[cc];
#pragma unroll
            for (int reg = 0; reg < 4; ++reg) {
                int node = nbase + reg;
                if (node < N) pbuf[(size_t)node * 64 + cc] = bfb(ae[nt][reg] + bias2);
            }
        }
    }
}

// ---------------- fused X2-gather + Cheb MFMA + (e1 | pool) , KDIM=64 ----------------
// X0 = hD (bf16), X1 = xd*dsq (accM trick), X2 = -2*dinv*aggr(xd) - hD gathered in-block.

template <bool POOLOUT>
__global__ __launch_bounds__(256) void k_cheb64f(const unsigned short* __restrict__ X0,
                                                 const unsigned short* __restrict__ xd,
                                                 const int2* __restrict__ row_be, const int* __restrict__ csr,
                                                 const float* __restrict__ dinv, const float* __restrict__ dsq,
                                                 const float* __restrict__ W, const float* __restrict__ bvec,
                                                 const float* __restrict__ Wt, const float* __restrict__ Wp,
                                                 const float* __restrict__ bt, const float* __restrict__ bp,
                                                 unsigned short* __restrict__ md, unsigned short* __restrict__ pbuf,
                                                 const int* __restrict__ gid, float* __restrict__ pout,
                                                 int zoff, int N) {
    constexpr int SX = 200;             // 192 + 8
    __shared__ unsigned short S[17408]; // Ws 64x200 (12800) + Xs2 64x72 (4608); e1 reuses first 13824
    unsigned short* Ws = S;
    unsigned short* Xs2 = S + 12800;
    int t = threadIdx.x;
    int wave = t >> 6, lane = t & 63;

    for (int idx = t; idx < 12288; idx += 256) {
        int a = idx / 4096;
        int r = idx & 4095;
        int k = r >> 6, n = r & 63;
        Ws[n * SX + a * 64 + k] = bfb(W[idx]);
    }

    // in-block X2 gather: each wave covers 16 rows
    {
        int g = lane >> 3;
        int co = (lane & 7) * 16;
        const char* base = (const char*)xd + co;
        for (int i = 0; i < 16; ++i) {
            int ln = wave * 16 + i;
            int gn = blockIdx.x * 64 + ln; if (gn >= N) gn = N - 1;
            int2 be = row_be[gn];
            int beg = be.x, end = be.y;
            int deg = end - beg;
            int myOff = (lane < deg) ? (csr[beg + lane] << 7) : zoff;
            float a0 = 0.f, a1 = 0.f, a2 = 0.f, a3 = 0.f, a4 = 0.f, a5 = 0.f, a6 = 0.f, a7 = 0.f;
            {
                int o0 = __shfl(myOff, g);
                int o1 = __shfl(myOff, 8 + g);
                int o2 = __shfl(myOff, 16 + g);
                int o3 = __shfl(myOff, 24 + g);
                uint4 x0 = *(const uint4*)(base + o0);
                uint4 x1 = *(const uint4*)(base + o1);
                uint4 x2 = *(const uint4*)(base + o2);
                uint4 x3 = *(const uint4*)(base + o3);
                acc2(a0, a1, x0.x); acc2(a2, a3, x0.y); acc2(a4, a5, x0.z); acc2(a6, a7, x0.w);
                acc2(a0, a1, x1.x); acc2(a2, a3, x1.y); acc2(a4, a5, x1.z); acc2(a6, a7, x1.w);
                acc2(a0, a1, x2.x); acc2(a2, a3, x2.y); acc2(a4, a5, x2.z); acc2(a6, a7, x2.w);
                acc2(a0, a1, x3.x); acc2(a2, a3, x3.y); acc2(a4, a5, x3.z); acc2(a6, a7, x3.w);
            }
            if (deg > 32) {
                int dmain = deg < 64 ? deg : 64;
                for (int j = 32; j < dmain; j += 8) {
                    int o = __shfl(myOff, j + g);
                    uint4 x = *(const uint4*)(base + o);
                    acc2(a0, a1, x.x); acc2(a2, a3, x.y); acc2(a4, a5, x.z); acc2(a6, a7, x.w);
                }
                for (int e = beg + 64; e < end; e += 8) {
                    int idx = e + g;
                    int s = csr[idx < end ? idx : end - 1];
                    uint4 x = *(const uint4*)(base + (s << 7));
                    if (idx < end) {
                        acc2(a0, a1, x.x); acc2(a2, a3, x.y); acc2(a4, a5, x.z); acc2(a6, a7, x.w);
                    }
                }
            }
            a0 += __shfl_xor(a0, 8); a0 += __shfl_xor(a0, 16); a0 += __shfl_xor(a0, 32);
            a1 += __shfl_xor(a1, 8); a1 += __shfl_xor(a1, 16); a1 += __shfl_xor(a1, 32);
            a2 += __shfl_xor(a2, 8); a2 += __shfl_xor(a2, 16); a2 += __shfl_xor(a2, 32);
            a3 += __shfl_xor(a3, 8); a3 += __shfl_xor(a3, 16); a3 += __shfl_xor(a3, 32);
            a4 += __shfl_xor(a4, 8); a4 += __shfl_xor(a4, 16); a4 += __shfl_xor(a4, 32);
            a5 += __shfl_xor(a5, 8); a5 += __shfl_xor(a5, 16); a5 += __shfl_xor(a5, 32);
            a6 += __shfl_xor(a6, 8); a6 += __shfl_xor(a6, 16); a6 += __shfl_xor(a6, 32);
            a7 += __shfl_xor(a7, 8); a7 += __shfl_xor(a7, 16); a7 += __shfl_xor(a7, 32);
            if (g == 0) {
                float dn = dinv[gn];
                float a[8] = { a0, a1, a2, a3, a4, a5, a6, a7 };
                uint4 zv = *(const uint4*)((const char*)X0 + (size_t)gn * 128 + co);
                unsigned zd[4] = { zv.x, zv.y, zv.z, zv.w };
                uint4 u;
                unsigned* pu = (unsigned*)&u;
#pragma unroll
                for (int q = 0; q < 4; ++q) {
                    union { unsigned uu; float f; } lo, hi;
                    lo.uu = zd[q] << 16; hi.uu = zd[q] & 0xffff0000u;
                    float vlo = -2.f * dn * a[2 * q] - lo.f;
                    float vhi = -2.f * dn * a[2 * q + 1] - hi.f;
                    pu[q] = (unsigned)bfb(vlo) | ((unsigned)bfb(vhi) << 16);
                }
                *(uint4*)&Xs2[ln * 72 + (lane & 7) * 8] = u;
            }
        }
    }
    __syncthreads();

    int fi = lane & 15, quad = lane >> 4;
    int arow = wave * 16 + fi;
    int arow_node = blockIdx.x * 64 + arow;
    int anode = arow_node < N ? arow_node : N - 1;

    floatx4 accA[4], accM[4];
#pragma unroll
    for (int i = 0; i < 4; ++i) { accA[i] = (floatx4){0.f,0.f,0.f,0.f}; accM[i] = (floatx4){0.f,0.f,0.f,0.f}; }
#pragma unroll
    for (int ks = 0; ks < 6; ++ks) {
        int kidx = ks * 32 + quad * 8;
        int seg = kidx >> 6;
        short8 af;
        if (seg == 0) {
            af = *(const short8*)&X0[(size_t)anode * 64 + (kidx & 63)];
        } else if (seg == 1) {
            af = *(const short8*)&xd[(size_t)anode * 64 + (kidx & 63)];
        } else {
            af = *(const short8*)&Xs2[arow * 72 + (kidx & 63)];
        }
        short8 b0 = *(const short8*)&Ws[(0 * 16 + fi) * SX + kidx];
        short8 b1 = *(const short8*)&Ws[(1 * 16 + fi) * SX + kidx];
        short8 b2 = *(const short8*)&Ws[(2 * 16 + fi) * SX + kidx];
        short8 b3 = *(const short8*)&Ws[(3 * 16 + fi) * SX + kidx];
        if (ks >= 2 && ks < 4) {
            accM[0] = __builtin_amdgcn_mfma_f32_16x16x32_bf16(af, b0, accM[0], 0, 0, 0);
            accM[1] = __builtin_amdgcn_mfma_f32_16x16x32_bf16(af, b1, accM[1], 0, 0, 0);
            accM[2] = __builtin_amdgcn_mfma_f32_16x16x32_bf16(af, b2, accM[2], 0, 0, 0);
            accM[3] = __builtin_amdgcn_mfma_f32_16x16x32_bf16(af, b3, accM[3], 0, 0, 0);
        } else {
            accA[0] = __builtin_amdgcn_mfma_f32_16x16x32_bf16(af, b0, accA[0], 0, 0, 0);
            accA[1] = __builtin_amdgcn_mfma_f32_16x16x32_bf16(af, b1, accA[1], 0, 0, 0);
            accA[2] = __builtin_amdgcn_mfma_f32_16x16x32_bf16(af, b2, accA[2], 0, 0, 0);
            accA[3] = __builtin_amdgcn_mfma_f32_16x16x32_bf16(af, b3, accA[3], 0, 0, 0);
        }
    }

    int nbase0 = blockIdx.x * 64 + wave * 16;
    int nbase = nbase0 + quad * 4;
    float dd[4];
#pragma unroll
    for (int reg = 0; reg < 4; ++reg) {
        int node = nbase + reg;
        dd[reg] = dsq[node < N ? node : N - 1];
    }
    float rv[4][4];
#pragma unroll
    for (int nt = 0; nt < 4; ++nt) {
        float bias = bvec[nt * 16 + fi];
#pragma unroll
        for (int reg = 0; reg < 4; ++reg)
            rv[nt][reg] = fmaxf(accA[nt][reg] + accM[nt][reg] * dd[reg] + bias, 0.f);
    }

    if constexpr (POOLOUT) {
        int gfirst = gid[nbase0 < N ? nbase0 : N - 1];
        int lastn = nbase0 + 15;
        int glast = gid[lastn < N ? lastn : N - 1];
        bool uniform = (lastn < N) && (gfirst == glast);
        if (uniform) {
#pragma unroll
            for (int nt = 0; nt < 4; ++nt) {
                float s = (rv[nt][0] + rv[nt][1]) + (rv[nt][2] + rv[nt][3]);
                s += __shfl_xor(s, 16); s += __shfl_xor(s, 32);
                if (quad == 0) atomicAdd(&pout[(size_t)gfirst * 64 + nt * 16 + fi], s);
            }
        } else {
#pragma unroll
            for (int reg = 0; reg < 4; ++reg) {
                int node = nbase + reg;
                if (node < N) {
                    int g = gid[node];
#pragma unroll
                    for (int nt = 0; nt < 4; ++nt)
                        atomicAdd(&pout[(size_t)g * 64 + nt * 16 + fi], rv[nt][reg]);
                }
            }
        }
    } else {
        __syncthreads();
        unsigned short* Hs = S;
        unsigned short* W2l = S + 64 * 72;
        int lrow = wave * 16 + quad * 4;
#pragma unroll
        for (int nt = 0; nt < 4; ++nt)
#pragma unroll
            for (int reg = 0; reg < 4; ++reg)
                Hs[(lrow + reg) * 72 + nt * 16 + fi] = bfb(rv[nt][reg]);
        for (int idx = t; idx < 4096; idx += 256) {
            int k = idx >> 6, n = idx & 63;
            float wt = Wt[idx];
            W2l[n * 72 + k] = bfb(wt);
            W2l[(64 + n) * 72 + k] = bfb(wt + Wp[idx]);
        }
        __syncthreads();
        floatx4 ae[8];
#pragma unroll
        for (int i = 0; i < 8; ++i) ae[i] = (floatx4){0.f,0.f,0.f,0.f};
#pragma unroll
        for (int ks = 0; ks < 2; ++ks) {
            short8 af = *(const short8*)&Hs[arow * 72 + ks * 32 + quad * 8];
#pragma unroll
            for (int nt = 0; nt < 8; ++nt) {
                short8 bf = *(const short8*)&W2l[(nt * 16 + fi) * 72 + ks * 32 + quad * 8];
                ae[nt] = __builtin_amdgcn_mfma_f32_16x16x32_bf16(af, bf, ae[nt], 0, 0, 0);
            }
        }
#pragma unroll
        for (int nt = 0; nt < 8; ++nt) {
            int col = nt * 16 + fi;
            if (col < 64) {
#pragma unroll
                for (int reg = 0; reg < 4; ++reg) {
                    int node = nbase + reg;
                    if (node < N) {
                        unsigned u = (unsigned)bfb(ae[nt][reg]) ^ 0x8000u;
                        unsigned key = (u & 0x8000u) ? (~u & 0xffffu) : (u | 0x8000u);
                        md[(size_t)node * 64 + col] = (unsigned short)key;
                    }
                }
            } else {
                int cc = col - 64;
                float bias2 = bt[cc] + bp[cc];
#pragma unroll
                for (int reg = 0; reg < 4; ++reg) {
                    int node = nbase + reg;
                    if (node < N) pbuf[(size_t)node * 64 + cc] = bfb(ae[nt][reg] + bias2);
                }
            }
        }
    }
}

// ---------------- EdgeConv stage 2: padded branch-free packed key-max ----------------

__global__ __launch_bounds__(256) void k_e2_b(const unsigned short* __restrict__ md,
                                              const unsigned short* __restrict__ pbuf,
                                              const int2* __restrict__ row_be, const int* __restrict__ csr,
                                              const float* __restrict__ dinv, unsigned short* __restrict__ out,
                                              unsigned short* __restrict__ outd, int zoff, int N) {
    int node = blockIdx.x * 4 + (threadIdx.x >> 6);
    if (node >= N) return;
    int lane = threadIdx.x & 63;
    int g = lane >> 3;
    int co = (lane & 7) * 16;
    int2 be = row_be[node];
    int beg = be.x, end = be.y;
    int deg = end - beg;
    int dmain = deg < 64 ? deg : 64;
    int li = lane < dmain ? lane : dmain - 1;
    int myOff = (deg > 0) ? (csr[beg + li] << 7) : zoff;
    const char* base = (const char*)md + co;
    unsigned k0 = 0, k1 = 0, k2 = 0, k3 = 0;
    {
        int o0 = __shfl(myOff, g);
        int o1 = __shfl(myOff, 8 + g);
        int o2 = __shfl(myOff, 16 + g);
        int o3 = __shfl(myOff, 24 + g);
        uint4 x0 = *(const uint4*)(base + o0);
        uint4 x1 = *(const uint4*)(base + o1);
        uint4 x2 = *(const uint4*)(base + o2);
        uint4 x3 = *(const uint4*)(base + o3);
        k0 = pkmaxu16(k0, x0.x); k1 = pkmaxu16(k1, x0.y); k2 = pkmaxu16(k2, x0.z); k3 = pkmaxu16(k3, x0.w);
        k0 = pkmaxu16(k0, x1.x); k1 = pkmaxu16(k1, x1.y); k2 = pkmaxu16(k2, x1.z); k3 = pkmaxu16(k3, x1.w);
        k0 = pkmaxu16(k0, x2.x); k1 = pkmaxu16(k1, x2.y); k2 = pkmaxu16(k2, x2.z); k3 = pkmaxu16(k3, x2.w);
        k0 = pkmaxu16(k0, x3.x); k1 = pkmaxu16(k1, x3.y); k2 = pkmaxu16(k2, x3.z); k3 = pkmaxu16(k3, x3.w);
    }
    if (deg > 32) {
        for (int j = 32; j < dmain; j += 8) {
            int o = __shfl(myOff, j + g);
            uint4 x = *(const uint4*)(base + o);
            k0 = pkmaxu16(k0, x.x); k1 = pkmaxu16(k1, x.y); k2 = pkmaxu16(k2, x.z); k3 = pkmaxu16(k3, x.w);
        }
        for (int e = beg + 64; e < end; e += 8) {
            int idx = e + g;
            int s = csr[idx < end ? idx : end - 1];
            uint4 x = *(const uint4*)(base + (s << 7));
            k0 = pkmaxu16(k0, x.x); k1 = pkmaxu16(k1, x.y); k2 = pkmaxu16(k2, x.z); k3 = pkmaxu16(k3, x.w);
        }
    }
    k0 = pkmaxu16(k0, __shfl_xor((int)k0, 8)); k0 = pkmaxu16(k0, __shfl_xor((int)k0, 16)); k0 = pkmaxu16(k0, __shfl_xor((int)k0, 32));
    k1 = pkmaxu16(k1, __shfl_xor((int)k1, 8)); k1 = pkmaxu16(k1, __shfl_xor((int)k1, 16)); k1 = pkmaxu16(k1, __shfl_xor((int)k1, 32));
    k2 = pkmaxu16(k2, __shfl_xor((int)k2, 8)); k2 = pkmaxu16(k2, __shfl_xor((int)k2, 16)); k2 = pkmaxu16(k2, __shfl_xor((int)k2, 32));
    k3 = pkmaxu16(k3, __shfl_xor((int)k3, 8)); k3 = pkmaxu16(k3, __shfl_xor((int)k3, 16)); k3 = pkmaxu16(k3, __shfl_xor((int)k3, 32));
    if (g == 0) {
        unsigned kd[4] = { k0, k1, k2, k3 };
        float a[8];
#pragma unroll
        for (int i = 0; i < 4; ++i) {
            unsigned klo = kd[i] & 0xffffu, khi = kd[i] >> 16;
            unsigned short tlo = (klo & 0x8000u) ? (unsigned short)(klo & 0x7fffu) : (unsigned short)(~klo & 0xffffu);
            unsigned short thi = (khi & 0x8000u) ? (unsigned short)(khi & 0x7fffu) : (unsigned short)(~khi & 0xffffu);
            a[2 * i] = bf2f(tlo);
            a[2 * i + 1] = bf2f(thi);
        }
        float r[8];
        if (end > beg) {
            uint4 pk = *(const uint4*)((const char*)pbuf + (size_t)node * 128 + co);
            unsigned pd4[4] = { pk.x, pk.y, pk.z, pk.w };
#pragma unroll
            for (int i = 0; i < 4; ++i) {
                r[2 * i]     = fmaxf(bf2f((unsigned short)(pd4[i] & 0xffffu)) + a[2 * i], 0.f);
                r[2 * i + 1] = fmaxf(bf2f((unsigned short)(pd4[i] >> 16)) + a[2 * i + 1], 0.f);
            }
        } else {
#pragma unroll
            for (int i = 0; i < 8; ++i) r[i] = 0.f;
        }
        float dn = dinv[node];
        size_t rb = (size_t)node * 128 + co;
        uint4 ub, ud;
        unsigned* pb = (unsigned*)&ub;
        unsigned* pd = (unsigned*)&ud;
#pragma unroll
        for (int i = 0; i < 4; ++i) {
            pb[i] = (unsigned)bfb(r[2 * i]) | ((unsigned)bfb(r[2 * i + 1]) << 16);
            pd[i] = (unsigned)bfb(r[2 * i] * dn) | ((unsigned)bfb(r[2 * i + 1] * dn) << 16);
        }
        *(uint4*)((char*)out + rb) = ub;
        *(uint4*)((char*)outd + rb) = ud;
    }
}

// ---------------- final divide: per-graph count via binary search on sorted gid ----------------

__global__ __launch_bounds__(256) void k_div(float* __restrict__ out, const float* __restrict__ pout,
                                             const int* __restrict__ gid, int N, int total) {
    int i = blockIdx.x * blockDim.x + threadIdx.x;
    if (i >= total) return;
    int g = i >> 6;
    int lo = 0, hi = N;
    while (lo < hi) { int m = (lo + hi) >> 1; if (gid[m] < g) lo = m + 1; else hi = m; }
    int s = lo;
    hi = N;
    while (lo < hi) { int m = (lo + hi) >> 1; if (gid[m] < g + 1) lo = m + 1; else hi = m; }
    float c = (float)(lo - s);
    out[i] = pout[i] / fmaxf(c, 1.f);
}

// ---------------- launcher ----------------

extern "C" void kernel_launch(void* const* d_in, const int* in_sizes, int n_in,
                              void* d_out, int out_size, void* d_ws, size_t ws_size,
                              hipStream_t stream) {
    const float* feat = (const float*)d_in[0];
    const int* src = (const int*)d_in[1];
    const int* dst = (const int*)d_in[2];
    const int* gid = (const int*)d_in[3];
    const float* W1 = (const float*)d_in[4];  const float* b1 = (const float*)d_in[5];
    const float* W2 = (const float*)d_in[6];  const float* b2 = (const float*)d_in[7];
    const float* W3 = (const float*)d_in[8];  const float* b3 = (const float*)d_in[9];
    const float* Wt1 = (const float*)d_in[10]; const float* bt1 = (const float*)d_in[11];
    const float* Wp1 = (const float*)d_in[12]; const float* bp1 = (const float*)d_in[13];
    const float* Wt2 = (const float*)d_in[14]; const float* bt2 = (const float*)d_in[15];
    const float* Wp2 = (const float*)d_in[16]; const float* bp2 = (const float*)d_in[17];
    float* out = (float*)d_out;

    const int N = in_sizes[0] / 16;
    const int E = in_sizes[1];
    const int G = out_size / 64;
    const int nb = (N + 255) >> 8;      // buckets (<= 512)

    char* p = (char*)d_ws;
    auto alloc = [&](size_t nbytes) {
        void* r = (void*)p;
        p += (nbytes + 255) & ~(size_t)255;
        return r;
    };
    // zero-block: bcur | zpage | pout contiguous -> single memset
    int* bcur     = (int*)alloc(512 * 4);
    char* zpage   = (char*)alloc(256);
    float* pout   = (float*)alloc((size_t)G * 64 * 4);
    size_t zspan  = (size_t)((char*)pout - (char*)bcur) + (((size_t)G * 64 * 4 + 255) & ~(size_t)255);
    int2* row_be  = (int2*)alloc((size_t)N * 8);
    int* csr      = (int*)alloc(((size_t)nb * SLABC + 1024) * 4);
    float* dinv   = (float*)alloc((size_t)N * 4);
    float* dsq    = (float*)alloc((size_t)N * 4);
    float* bufA   = (float*)alloc((size_t)N * 64 * 4);   // ebuf slab (CSR build only)
    float* bufC   = (float*)alloc((size_t)N * 64 * 4);   // hd | xd (bf16 halves)
    unsigned short* hD   = (unsigned short*)alloc((size_t)N * 64 * 2);
    unsigned short* md   = (unsigned short*)alloc((size_t)N * 64 * 2);
    unsigned short* pbuf = (unsigned short*)alloc((size_t)N * 64 * 2);

    unsigned* ebuf = (unsigned*)bufA;                    // slab: nb*SLABC entries
    unsigned short* hd = (unsigned short*)bufC;          // dinv-scaled h (gather operand)
    unsigned short* xd = hd + (size_t)N * 64;            // dinv-scaled X1
    unsigned short* xA16 = (unsigned short*)bufA;        // layer-1 X1 bf16 (ebuf dead after finish)

    const int zo_hd = (int)((char*)zpage - (char*)hd);
    const int zo_xd = (int)((char*)zpage - (char*)xd);
    const int zo_md = (int)((char*)zpage - (char*)md);

    hipMemsetAsync(bcur, 0, zspan, stream);

    const int nbw = (N + 3) / 4;
    const int nbt = (N + 63) / 64;
    const int npart = (E + PCHUNK - 1) / PCHUNK;

    // ---- slab-bucket CSR build (2 launches; k_finish fuses feat->bf16 prescale)
    k_partA<<<npart, 256, 0, stream>>>(src, dst, bcur, ebuf, E);
    k_finish<<<nb, 256, 0, stream>>>(ebuf, bcur, row_be, dinv, dsq, csr, feat, hd, N);

    // ---- Cheb layer 1 (IN=16): X1 pass, then fused [X2-gather + cheb + e1]
    k_aggr16<<<nbw, 256, 0, stream>>>(hd, dinv, row_be, csr, xA16, xd, zo_hd, N);
    k_cheb16f<<<nbt, 256, 0, stream>>>(feat, xA16, xd, row_be, csr, dinv, W1, b1,
                                       Wt1, Wp1, bt1, bp1, md, pbuf, zo_xd, N);
    k_e2_b<<<nbw, 256, 0, stream>>>(md, pbuf, row_be, csr, dinv, hD, hd, zo_md, N);

    // ---- Cheb layer 2: X1 pass, fused [X2-gather + cheb + e1]
    k_aggr64<<<nbw, 256, 0, stream>>>(hd, dinv, row_be, csr, xd, zo_hd, N);
    k_cheb64f<false><<<nbt, 256, 0, stream>>>(hD, xd, row_be, csr, dinv, dsq, W2, b2,
                                              Wt2, Wp2, bt2, bp2, md, pbuf, nullptr, nullptr, zo_xd, N);
    k_e2_b<<<nbw, 256, 0, stream>>>(md, pbuf, row_be, csr, dinv, hD, hd, zo_md, N);

    // ---- Cheb layer 3: X1 pass, fused [X2-gather + cheb + pool]
    k_aggr64<<<nbw, 256, 0, stream>>>(hd, dinv, row_be, csr, xd, zo_hd, N);
    k_cheb64f<true><<<nbt, 256, 0, stream>>>(hD, xd, row_be, csr, dinv, dsq, W3, b3,
                                             nullptr, nullptr, nullptr, nullptr,
                                             nullptr, nullptr, gid, pout, zo_xd, N);

    // ---- divide by per-graph counts (binary search on sorted gid)
    k_div<<<(out_size + 255) / 256, 256, 0, stream>>>(out, pout, gid, N, out_size);
}

// Round 9
// 516.496 us; speedup vs baseline: 1.0595x; 1.0595x over previous
//
#include <hip/hip_runtime.h>
#include <hip/hip_bf16.h>
#include <math.h>

typedef __attribute__((ext_vector_type(8))) short short8;
typedef __attribute__((ext_vector_type(4))) float floatx4;

__device__ __forceinline__ unsigned short bfb(float x) {
    union { __hip_bfloat16 h; unsigned short u; } c;
    c.h = __float2bfloat16(x);
    return c.u;
}
__device__ __forceinline__ float bf2f(unsigned short u) {
    union { unsigned int i; float f; } c;
    c.i = ((unsigned int)u) << 16;
    return c.f;
}
// accumulate the two bf16 halves of a dword into two f32 accumulators
__device__ __forceinline__ void acc2(float& lo, float& hi, unsigned d) {
    union { unsigned u; float f; } a, b;
    a.u = d << 16;
    b.u = d & 0xffff0000u;
    lo += a.f; hi += b.f;
}
// packed unsigned 16-bit max (gfx9 VOP3P, inherited on CDNA4)
__device__ __forceinline__ unsigned pkmaxu16(unsigned a, unsigned b) {
    unsigned d;
    asm("v_pk_max_u16 %0, %1, %2" : "=v"(d) : "v"(a), "v"(b));
    return d;
}

#define SLABC 5120          // slab capacity per 256-node bucket (Poisson(4096)+16 sigma)
#define PCHUNK 8192

// ---------------- slab-bucket CSR build (2 kernels, no scan) ----------------

__global__ __launch_bounds__(256) void k_partA(const int* __restrict__ src, const int* __restrict__ dst,
                                               int* __restrict__ bcur, unsigned* __restrict__ ebuf, int E) {
    __shared__ int h[512];
    __shared__ int base[512];
    int t = threadIdx.x;
    for (int i = t; i < 512; i += 256) h[i] = 0;
    __syncthreads();
    int start = blockIdx.x * PCHUNK;
    int end = start + PCHUNK < E ? start + PCHUNK : E;
    for (int i = start + t; i < end; i += 256) atomicAdd(&h[dst[i] >> 8], 1);
    __syncthreads();
    for (int i = t; i < 512; i += 256) {
        int c = h[i];
        base[i] = c ? atomicAdd(&bcur[i], c) : 0;
        h[i] = 0;
    }
    __syncthreads();
    for (int i = start + t; i < end; i += 256) {
        int d = dst[i];
        int b = d >> 8;
        int r = atomicAdd(&h[b], 1);
        ebuf[b * SLABC + base[b] + r] = ((unsigned)src[i] << 8) | (unsigned)(d & 255);
    }
}

// per-bucket: node degrees, local scan, row_be/dinv/dsq, csr scatter, feat->bf16 prescale
__global__ __launch_bounds__(256) void k_finish(const unsigned* __restrict__ ebuf, const int* __restrict__ bcur,
                                                int2* __restrict__ row_be, float* __restrict__ dinv,
                                                float* __restrict__ dsq, int* __restrict__ csr,
                                                const float* __restrict__ feat, unsigned short* __restrict__ hd,
                                                int N) {
    __shared__ int h[256];
    __shared__ int sc[256];
    __shared__ int cur[256];
    int b = blockIdx.x, t = threadIdx.x;
    h[t] = 0;
    __syncthreads();
    int beg = b * SLABC, end = beg + bcur[b];
    for (int e = beg + t; e < end; e += 256) atomicAdd(&h[ebuf[e] & 255], 1);
    __syncthreads();
    int v = h[t];
    sc[t] = v;
    __syncthreads();
    for (int off = 1; off < 256; off <<= 1) {
        int x = (t >= off) ? sc[t - off] : 0;
        __syncthreads();
        sc[t] += x;
        __syncthreads();
    }
    int node = (b << 8) + t;
    int excl = beg + sc[t] - v;
    if (node < N) {
        row_be[node] = make_int2(excl, excl + v);
        float dg = (float)(v > 1 ? v : 1);
        float dv = rsqrtf(dg);
        dinv[node] = dv;
        dsq[node] = sqrtf(dg);
        const float* f = &feat[(size_t)node * 16];
#pragma unroll
        for (int k = 0; k < 16; k += 4) {
            float4 x = *(const float4*)&f[k];
            ushort4 u = { bfb(x.x * dv), bfb(x.y * dv), bfb(x.z * dv), bfb(x.w * dv) };
            *(ushort4*)&hd[(size_t)node * 16 + k] = u;
        }
    }
    cur[t] = excl;
    __syncthreads();
    for (int e = beg + t; e < end; e += 256) {
        unsigned ed = ebuf[e];
        int pos = atomicAdd(&cur[ed & 255], 1);
        csr[pos] = (int)(ed >> 8);
    }
}

// ---------------- 16-dim Chebyshev aggregation, padded branch-free (bf16 out) ----------------

__global__ __launch_bounds__(256) void k_aggr16(const unsigned short* __restrict__ Xd, const float* __restrict__ Z,
                                                const float* __restrict__ dinv,
                                                const int2* __restrict__ row_be, const int* __restrict__ csr,
                                                unsigned short* __restrict__ outb, unsigned short* __restrict__ outd,
                                                float alpha, float beta, int zoff, int N) {
    int node = blockIdx.x * 4 + (threadIdx.x >> 6);
    if (node >= N) return;
    int lane = threadIdx.x & 63;
    int g = lane >> 2;                  // 16 edge groups
    int co = (lane & 3) * 8;            // byte offset of this lane's 4 cols
    int2 be = row_be[node];
    int beg = be.x, end = be.y;
    int deg = end - beg;
    int myOff = (lane < deg) ? (csr[beg + lane] << 5) : zoff;   // 32B rows; pad -> zero page
    const char* base = (const char*)Xd + co;
    float a0 = 0.f, a1 = 0.f, a2 = 0.f, a3 = 0.f;
    {
        int o0 = __shfl(myOff, g);
        int o1 = __shfl(myOff, 16 + g);
        ushort4 x0 = *(const ushort4*)(base + o0);
        ushort4 x1 = *(const ushort4*)(base + o1);
        a0 += bf2f(x0.x); a1 += bf2f(x0.y); a2 += bf2f(x0.z); a3 += bf2f(x0.w);
        a0 += bf2f(x1.x); a1 += bf2f(x1.y); a2 += bf2f(x1.z); a3 += bf2f(x1.w);
    }
    if (deg > 32) {
        int dmain = deg < 64 ? deg : 64;
        for (int j = 32; j < dmain; j += 16) {
            int o = __shfl(myOff, j + g);
            ushort4 x = *(const ushort4*)(base + o);
            a0 += bf2f(x.x); a1 += bf2f(x.y); a2 += bf2f(x.z); a3 += bf2f(x.w);
        }
        for (int e = beg + 64; e < end; e += 16) {
            int idx = e + g;
            int s = csr[idx < end ? idx : end - 1];
            ushort4 x = *(const ushort4*)(base + (s << 5));
            if (idx < end) {
                a0 += bf2f(x.x); a1 += bf2f(x.y); a2 += bf2f(x.z); a3 += bf2f(x.w);
            }
        }
    }
    a0 += __shfl_xor(a0, 4); a0 += __shfl_xor(a0, 8); a0 += __shfl_xor(a0, 16); a0 += __shfl_xor(a0, 32);
    a1 += __shfl_xor(a1, 4); a1 += __shfl_xor(a1, 8); a1 += __shfl_xor(a1, 16); a1 += __shfl_xor(a1, 32);
    a2 += __shfl_xor(a2, 4); a2 += __shfl_xor(a2, 8); a2 += __shfl_xor(a2, 16); a2 += __shfl_xor(a2, 32);
    a3 += __shfl_xor(a3, 4); a3 += __shfl_xor(a3, 8); a3 += __shfl_xor(a3, 16); a3 += __shfl_xor(a3, 32);
    if (g == 0) {
        int c4 = (lane & 3) * 4;
        float dn = dinv[node];
        float v0 = alpha * dn * a0;
        float v1 = alpha * dn * a1;
        float v2 = alpha * dn * a2;
        float v3 = alpha * dn * a3;
        if (Z) {
            float4 zv = *(const float4*)&Z[(size_t)node * 16 + c4];
            v0 += beta * zv.x; v1 += beta * zv.y; v2 += beta * zv.z; v3 += beta * zv.w;
        }
        ushort4 ub = { bfb(v0), bfb(v1), bfb(v2), bfb(v3) };
        *(ushort4*)&outb[(size_t)node * 16 + c4] = ub;
        if (outd) {
            ushort4 u = { bfb(v0 * dn), bfb(v1 * dn), bfb(v2 * dn), bfb(v3 * dn) };
            *(ushort4*)&outd[(size_t)node * 16 + c4] = u;
        }
    }
}

// ---------------- 64-dim Chebyshev aggregation, padded branch-free ----------------
// outb optional (X1 pass writes only the dinv-scaled copy; cheb rescales via dsq).

__global__ __launch_bounds__(256) void k_aggr64(const unsigned short* __restrict__ Xd,
                                                const unsigned short* __restrict__ Z,
                                                const float* __restrict__ dinv,
                                                const int2* __restrict__ row_be, const int* __restrict__ csr,
                                                unsigned short* __restrict__ outb, unsigned short* __restrict__ outd,
                                                float alpha, float beta, int zoff, int N) {
    int node = blockIdx.x * 4 + (threadIdx.x >> 6);
    if (node >= N) return;
    int lane = threadIdx.x & 63;
    int g = lane >> 3;                  // 8 edge groups
    int co = (lane & 7) * 16;           // byte offset of this lane's 8 cols
    int2 be = row_be[node];
    int beg = be.x, end = be.y;
    int deg = end - beg;
    int myOff = (lane < deg) ? (csr[beg + lane] << 7) : zoff;   // 128B rows; pad -> zero page
    const char* base = (const char*)Xd + co;
    float a0 = 0.f, a1 = 0.f, a2 = 0.f, a3 = 0.f, a4 = 0.f, a5 = 0.f, a6 = 0.f, a7 = 0.f;
    {
        int o0 = __shfl(myOff, g);
        int o1 = __shfl(myOff, 8 + g);
        int o2 = __shfl(myOff, 16 + g);
        int o3 = __shfl(myOff, 24 + g);
        uint4 x0 = *(const uint4*)(base + o0);
        uint4 x1 = *(const uint4*)(base + o1);
        uint4 x2 = *(const uint4*)(base + o2);
        uint4 x3 = *(const uint4*)(base + o3);
        acc2(a0, a1, x0.x); acc2(a2, a3, x0.y); acc2(a4, a5, x0.z); acc2(a6, a7, x0.w);
        acc2(a0, a1, x1.x); acc2(a2, a3, x1.y); acc2(a4, a5, x1.z); acc2(a6, a7, x1.w);
        acc2(a0, a1, x2.x); acc2(a2, a3, x2.y); acc2(a4, a5, x2.z); acc2(a6, a7, x2.w);
        acc2(a0, a1, x3.x); acc2(a2, a3, x3.y); acc2(a4, a5, x3.z); acc2(a6, a7, x3.w);
    }
    if (deg > 32) {
        int dmain = deg < 64 ? deg : 64;
        for (int j = 32; j < dmain; j += 8) {
            int o = __shfl(myOff, j + g);
            uint4 x = *(const uint4*)(base + o);
            acc2(a0, a1, x.x); acc2(a2, a3, x.y); acc2(a4, a5, x.z); acc2(a6, a7, x.w);
        }
        for (int e = beg + 64; e < end; e += 8) {
            int idx = e + g;
            int s = csr[idx < end ? idx : end - 1];
            uint4 x = *(const uint4*)(base + (s << 7));
            if (idx < end) {
                acc2(a0, a1, x.x); acc2(a2, a3, x.y); acc2(a4, a5, x.z); acc2(a6, a7, x.w);
            }
        }
    }
    a0 += __shfl_xor(a0, 8); a0 += __shfl_xor(a0, 16); a0 += __shfl_xor(a0, 32);
    a1 += __shfl_xor(a1, 8); a1 += __shfl_xor(a1, 16); a1 += __shfl_xor(a1, 32);
    a2 += __shfl_xor(a2, 8); a2 += __shfl_xor(a2, 16); a2 += __shfl_xor(a2, 32);
    a3 += __shfl_xor(a3, 8); a3 += __shfl_xor(a3, 16); a3 += __shfl_xor(a3, 32);
    a4 += __shfl_xor(a4, 8); a4 += __shfl_xor(a4, 16); a4 += __shfl_xor(a4, 32);
    a5 += __shfl_xor(a5, 8); a5 += __shfl_xor(a5, 16); a5 += __shfl_xor(a5, 32);
    a6 += __shfl_xor(a6, 8); a6 += __shfl_xor(a6, 16); a6 += __shfl_xor(a6, 32);
    a7 += __shfl_xor(a7, 8); a7 += __shfl_xor(a7, 16); a7 += __shfl_xor(a7, 32);
    if (g == 0) {                       // lanes 0..7 hold cols lane*8 .. lane*8+7
        float dn = dinv[node];
        float v[8] = { a0, a1, a2, a3, a4, a5, a6, a7 };
#pragma unroll
        for (int i = 0; i < 8; ++i) v[i] *= alpha * dn;
        size_t rb = (size_t)node * 128 + co;            // byte offset of this lane's span
        if (Z) {
            uint4 zv = *(const uint4*)((const char*)Z + rb);
            unsigned zd[4] = { zv.x, zv.y, zv.z, zv.w };
#pragma unroll
            for (int i = 0; i < 4; ++i) {
                union { unsigned u; float f; } lo, hi;
                lo.u = zd[i] << 16; hi.u = zd[i] & 0xffff0000u;
                v[2 * i] += beta * lo.f;
                v[2 * i + 1] += beta * hi.f;
            }
        }
        if (outb) {
            uint4 ub;
            unsigned* pb = (unsigned*)&ub;
#pragma unroll
            for (int i = 0; i < 4; ++i)
                pb[i] = (unsigned)bfb(v[2 * i]) | ((unsigned)bfb(v[2 * i + 1]) << 16);
            *(uint4*)((char*)outb + rb) = ub;
        }
        if (outd) {
            uint4 ud;
            unsigned* pd = (unsigned*)&ud;
#pragma unroll
            for (int i = 0; i < 4; ++i)
                pd[i] = (unsigned)bfb(v[2 * i] * dn) | ((unsigned)bfb(v[2 * i + 1] * dn) << 16);
            *(uint4*)((char*)outd + rb) = ud;
        }
    }
}

// ---------------- fused Cheb matmul (+ EdgeConv stage 1 | atomic mean-pool) ----------------
// KDIM=16: X0 = f32 feat, X1/X2 = bf16. KDIM=64: all bf16; X1 = dinv-scaled xd ->
// mid-K-segment accumulated separately and row-scaled by dsq (commutes with K-sum).
// FUSE_E1: cheb ReLU -> LDS -> e1 MFMA [m|p]; emits md keys + bf16 pbuf.
// POOLOUT: epilogue accumulates per-graph mean-pool (sorted gid -> wave-reduced atomics).

template <int KDIM, bool FUSE_E1, bool POOLOUT>
__global__ __launch_bounds__(256) void k_cheb(const void* __restrict__ X0v, const void* __restrict__ X1v,
                                              const void* __restrict__ X2v, const float* __restrict__ dsq,
                                              const float* __restrict__ W, const float* __restrict__ bvec,
                                              const float* __restrict__ Wt, const float* __restrict__ Wp,
                                              const float* __restrict__ bt, const float* __restrict__ bp,
                                              unsigned short* __restrict__ md, unsigned short* __restrict__ pbuf,
                                              const int* __restrict__ gid, float* __restrict__ pout, int N) {
    constexpr int KT = (KDIM == 16) ? 64 : 3 * KDIM;
    constexpr int SX = KT + 8;
    constexpr int PH1 = 2 * 64 * SX;
    constexpr int PH2 = FUSE_E1 ? (64 * 72 + 128 * 72) : 0;
    constexpr int SSZ = PH1 > PH2 ? PH1 : PH2;
    constexpr bool hasMid = (KDIM == 64);
    __shared__ unsigned short S[SSZ];
    unsigned short* Xs = S;
    unsigned short* Ws = S + 64 * SX;
    int t = threadIdx.x;

    {
        int sn = t & 63;
        int gn = blockIdx.x * 64 + sn; if (gn >= N) gn = N - 1;
        int k0 = (t >> 6) * (KDIM / 4);
        if constexpr (KDIM == 16) {
            // X0 f32 feat
            float4 v = *(const float4*)&((const float*)X0v)[(size_t)gn * 16 + k0];
            ushort4 u = { bfb(v.x), bfb(v.y), bfb(v.z), bfb(v.w) };
            *(ushort4*)&Xs[sn * SX + k0] = u;
            // X1, X2 bf16
            *(ushort4*)&Xs[sn * SX + 16 + k0] =
                *(const ushort4*)&((const unsigned short*)X1v)[(size_t)gn * 16 + k0];
            *(ushort4*)&Xs[sn * SX + 32 + k0] =
                *(const ushort4*)&((const unsigned short*)X2v)[(size_t)gn * 16 + k0];
            int kp = 48 + (t >> 6) * 4;
            ushort4 z = { 0, 0, 0, 0 };
            *(ushort4*)&Xs[sn * SX + kp] = z;
        } else {
            const unsigned short* Xp[3] = { (const unsigned short*)X0v, (const unsigned short*)X1v,
                                            (const unsigned short*)X2v };
#pragma unroll
            for (int a = 0; a < 3; ++a) {
#pragma unroll
                for (int i = 0; i < KDIM / 16; ++i) {
                    *(ushort4*)&Xs[sn * SX + a * KDIM + k0 + 4 * i] =
                        *(const ushort4*)&Xp[a][(size_t)gn * KDIM + k0 + 4 * i];
                }
            }
        }
    }
    for (int idx = t; idx < 3 * KDIM * 64; idx += 256) {
        int a = idx / (KDIM * 64);
        int r = idx % (KDIM * 64);
        int k = r >> 6, n = r & 63;
        Ws[n * SX + a * KDIM + k] = bfb(W[idx]);
    }
    if constexpr (KDIM == 16) {
        for (int idx = t; idx < 1024; idx += 256) {
            int n = idx & 63, k = 48 + (idx >> 6);
            Ws[n * SX + k] = 0;
        }
    }
    __syncthreads();

    int wave = t >> 6, lane = t & 63;
    int fi = lane & 15, quad = lane >> 4;
    int arow = wave * 16 + fi;

    floatx4 accA[4], accM[4];
#pragma unroll
    for (int i = 0; i < 4; ++i) { accA[i] = (floatx4){0.f,0.f,0.f,0.f}; accM[i] = (floatx4){0.f,0.f,0.f,0.f}; }
#pragma unroll
    for (int ks = 0; ks < KT / 32; ++ks) {
        short8 af = *(const short8*)&Xs[arow * SX + ks * 32 + quad * 8];
        short8 b0 = *(const short8*)&Ws[(0 * 16 + fi) * SX + ks * 32 + quad * 8];
        short8 b1 = *(const short8*)&Ws[(1 * 16 + fi) * SX + ks * 32 + quad * 8];
        short8 b2 = *(const short8*)&Ws[(2 * 16 + fi) * SX + ks * 32 + quad * 8];
        short8 b3 = *(const short8*)&Ws[(3 * 16 + fi) * SX + ks * 32 + quad * 8];
        if (hasMid && ks >= 2 && ks < 4) {
            accM[0] = __builtin_amdgcn_mfma_f32_16x16x32_bf16(af, b0, accM[0], 0, 0, 0);
            accM[1] = __builtin_amdgcn_mfma_f32_16x16x32_bf16(af, b1, accM[1], 0, 0, 0);
            accM[2] = __builtin_amdgcn_mfma_f32_16x16x32_bf16(af, b2, accM[2], 0, 0, 0);
            accM[3] = __builtin_amdgcn_mfma_f32_16x16x32_bf16(af, b3, accM[3], 0, 0, 0);
        } else {
            accA[0] = __builtin_amdgcn_mfma_f32_16x16x32_bf16(af, b0, accA[0], 0, 0, 0);
            accA[1] = __builtin_amdgcn_mfma_f32_16x16x32_bf16(af, b1, accA[1], 0, 0, 0);
            accA[2] = __builtin_amdgcn_mfma_f32_16x16x32_bf16(af, b2, accA[2], 0, 0, 0);
            accA[3] = __builtin_amdgcn_mfma_f32_16x16x32_bf16(af, b3, accA[3], 0, 0, 0);
        }
    }

    int nbase0 = blockIdx.x * 64 + wave * 16;
    int nbase = nbase0 + quad * 4;
    float dd[4];
#pragma unroll
    for (int reg = 0; reg < 4; ++reg) {
        if constexpr (hasMid) {
            int node = nbase + reg;
            dd[reg] = dsq[node < N ? node : N - 1];
        } else dd[reg] = 0.f;
    }
    float rv[4][4];
#pragma unroll
    for (int nt = 0; nt < 4; ++nt) {
        int col = nt * 16 + fi;
        float bias = bvec[col];
#pragma unroll
        for (int reg = 0; reg < 4; ++reg) {
            float v = accA[nt][reg] + bias;
            if constexpr (hasMid) v += accM[nt][reg] * dd[reg];
            rv[nt][reg] = fmaxf(v, 0.f);
        }
    }

    if constexpr (POOLOUT) {
        int gfirst = gid[nbase0 < N ? nbase0 : N - 1];
        int lastn = nbase0 + 15;
        int glast = gid[lastn < N ? lastn : N - 1];
        bool uniform = (lastn < N) && (gfirst == glast);     // wave-uniform branch
        if (uniform) {
#pragma unroll
            for (int nt = 0; nt < 4; ++nt) {
                float s = (rv[nt][0] + rv[nt][1]) + (rv[nt][2] + rv[nt][3]);
                s += __shfl_xor(s, 16); s += __shfl_xor(s, 32);
                if (quad == 0) atomicAdd(&pout[(size_t)gfirst * 64 + nt * 16 + fi], s);
            }
        } else {
#pragma unroll
            for (int reg = 0; reg < 4; ++reg) {
                int node = nbase + reg;
                if (node < N) {
                    int g = gid[node];
#pragma unroll
                    for (int nt = 0; nt < 4; ++nt)
                        atomicAdd(&pout[(size_t)g * 64 + nt * 16 + fi], rv[nt][reg]);
                }
            }
        }
    } else if constexpr (FUSE_E1) {
        __syncthreads();                    // phase-1 LDS dead
        unsigned short* Hs = S;             // 64 x 72
        unsigned short* W2l = S + 64 * 72;  // 128 x 72
        int lrow = wave * 16 + quad * 4;
#pragma unroll
        for (int nt = 0; nt < 4; ++nt)
#pragma unroll
            for (int reg = 0; reg < 4; ++reg)
                Hs[(lrow + reg) * 72 + nt * 16 + fi] = bfb(rv[nt][reg]);
        for (int idx = t; idx < 4096; idx += 256) {
            int k = idx >> 6, n = idx & 63;
            float wt = Wt[idx];
            W2l[n * 72 + k] = bfb(wt);
            W2l[(64 + n) * 72 + k] = bfb(wt + Wp[idx]);
        }
        __syncthreads();
        floatx4 ae[8];
#pragma unroll
        for (int i = 0; i < 8; ++i) ae[i] = (floatx4){0.f,0.f,0.f,0.f};
#pragma unroll
        for (int ks = 0; ks < 2; ++ks) {
            short8 af = *(const short8*)&Hs[arow * 72 + ks * 32 + quad * 8];
#pragma unroll
            for (int nt = 0; nt < 8; ++nt) {
                short8 bf = *(const short8*)&W2l[(nt * 16 + fi) * 72 + ks * 32 + quad * 8];
                ae[nt] = __builtin_amdgcn_mfma_f32_16x16x32_bf16(af, bf, ae[nt], 0, 0, 0);
            }
        }
#pragma unroll
        for (int nt = 0; nt < 8; ++nt) {
            int col = nt * 16 + fi;
            if (col < 64) {
#pragma unroll
                for (int reg = 0; reg < 4; ++reg) {
                    int node = nbase + reg;
                    if (node < N) {
                        unsigned u = (unsigned)bfb(ae[nt][reg]) ^ 0x8000u;
                        unsigned key = (u & 0x8000u) ? (~u & 0xffffu) : (u | 0x8000u);
                        md[(size_t)node * 64 + col] = (unsigned short)key;
                    }
                }
            } else {
                int cc = col - 64;
                float bias2 = bt[cc] + bp[cc];
#pragma unroll
                for (int reg = 0; reg < 4; ++reg) {
                    int node = nbase + reg;
                    if (node < N) pbuf[(size_t)node * 64 + cc] = bfb(ae[nt][reg] + bias2);
                }
            }
        }
    }
}

// ---------------- EdgeConv stage 2: padded branch-free packed key-max ----------------

__global__ __launch_bounds__(256) void k_e2_b(const unsigned short* __restrict__ md,
                                              const unsigned short* __restrict__ pbuf,
                                              const int2* __restrict__ row_be, const int* __restrict__ csr,
                                              const float* __restrict__ dinv, unsigned short* __restrict__ out,
                                              unsigned short* __restrict__ outd, int zoff, int N) {
    int node = blockIdx.x * 4 + (threadIdx.x >> 6);
    if (node >= N) return;
    int lane = threadIdx.x & 63;
    int g = lane >> 3;
    int co = (lane & 7) * 16;
    int2 be = row_be[node];
    int beg = be.x, end = be.y;
    int deg = end - beg;
    int dmain = deg < 64 ? deg : 64;
    int li = lane < dmain ? lane : dmain - 1;
    int myOff = (deg > 0) ? (csr[beg + li] << 7) : zoff;
    const char* base = (const char*)md + co;
    unsigned k0 = 0, k1 = 0, k2 = 0, k3 = 0;
    {
        int o0 = __shfl(myOff, g);
        int o1 = __shfl(myOff, 8 + g);
        int o2 = __shfl(myOff, 16 + g);
        int o3 = __shfl(myOff, 24 + g);
        uint4 x0 = *(const uint4*)(base + o0);
        uint4 x1 = *(const uint4*)(base + o1);
        uint4 x2 = *(const uint4*)(base + o2);
        uint4 x3 = *(const uint4*)(base + o3);
        k0 = pkmaxu16(k0, x0.x); k1 = pkmaxu16(k1, x0.y); k2 = pkmaxu16(k2, x0.z); k3 = pkmaxu16(k3, x0.w);
        k0 = pkmaxu16(k0, x1.x); k1 = pkmaxu16(k1, x1.y); k2 = pkmaxu16(k2, x1.z); k3 = pkmaxu16(k3, x1.w);
        k0 = pkmaxu16(k0, x2.x); k1 = pkmaxu16(k1, x2.y); k2 = pkmaxu16(k2, x2.z); k3 = pkmaxu16(k3, x2.w);
        k0 = pkmaxu16(k0, x3.x); k1 = pkmaxu16(k1, x3.y); k2 = pkmaxu16(k2, x3.z); k3 = pkmaxu16(k3, x3.w);
    }
    if (deg > 32) {
        for (int j = 32; j < dmain; j += 8) {
            int o = __shfl(myOff, j + g);
            uint4 x = *(const uint4*)(base + o);
            k0 = pkmaxu16(k0, x.x); k1 = pkmaxu16(k1, x.y); k2 = pkmaxu16(k2, x.z); k3 = pkmaxu16(k3, x.w);
        }
        for (int e = beg + 64; e < end; e += 8) {
            int idx = e + g;
            int s = csr[idx < end ? idx : end - 1];
            uint4 x = *(const uint4*)(base + (s << 7));
            k0 = pkmaxu16(k0, x.x); k1 = pkmaxu16(k1, x.y); k2 = pkmaxu16(k2, x.z); k3 = pkmaxu16(k3, x.w);
        }
    }
    k0 = pkmaxu16(k0, __shfl_xor((int)k0, 8)); k0 = pkmaxu16(k0, __shfl_xor((int)k0, 16)); k0 = pkmaxu16(k0, __shfl_xor((int)k0, 32));
    k1 = pkmaxu16(k1, __shfl_xor((int)k1, 8)); k1 = pkmaxu16(k1, __shfl_xor((int)k1, 16)); k1 = pkmaxu16(k1, __shfl_xor((int)k1, 32));
    k2 = pkmaxu16(k2, __shfl_xor((int)k2, 8)); k2 = pkmaxu16(k2, __shfl_xor((int)k2, 16)); k2 = pkmaxu16(k2, __shfl_xor((int)k2, 32));
    k3 = pkmaxu16(k3, __shfl_xor((int)k3, 8)); k3 = pkmaxu16(k3, __shfl_xor((int)k3, 16)); k3 = pkmaxu16(k3, __shfl_xor((int)k3, 32));
    if (g == 0) {
        unsigned kd[4] = { k0, k1, k2, k3 };
        float a[8];
#pragma unroll
        for (int i = 0; i < 4; ++i) {
            unsigned klo = kd[i] & 0xffffu, khi = kd[i] >> 16;
            unsigned short tlo = (klo & 0x8000u) ? (unsigned short)(klo & 0x7fffu) : (unsigned short)(~klo & 0xffffu);
            unsigned short thi = (khi & 0x8000u) ? (unsigned short)(khi & 0x7fffu) : (unsigned short)(~khi & 0xffffu);
            a[2 * i] = bf2f(tlo);
            a[2 * i + 1] = bf2f(thi);
        }
        float r[8];
        if (end > beg) {
            uint4 pk = *(const uint4*)((const char*)pbuf + (size_t)node * 128 + co);
            unsigned pd4[4] = { pk.x, pk.y, pk.z, pk.w };
#pragma unroll
            for (int i = 0; i < 4; ++i) {
                r[2 * i]     = fmaxf(bf2f((unsigned short)(pd4[i] & 0xffffu)) + a[2 * i], 0.f);
                r[2 * i + 1] = fmaxf(bf2f((unsigned short)(pd4[i] >> 16)) + a[2 * i + 1], 0.f);
            }
        } else {
#pragma unroll
            for (int i = 0; i < 8; ++i) r[i] = 0.f;
        }
        float dn = dinv[node];
        size_t rb = (size_t)node * 128 + co;
        uint4 ub, ud;
        unsigned* pb = (unsigned*)&ub;
        unsigned* pd = (unsigned*)&ud;
#pragma unroll
        for (int i = 0; i < 4; ++i) {
            pb[i] = (unsigned)bfb(r[2 * i]) | ((unsigned)bfb(r[2 * i + 1]) << 16);
            pd[i] = (unsigned)bfb(r[2 * i] * dn) | ((unsigned)bfb(r[2 * i + 1] * dn) << 16);
        }
        *(uint4*)((char*)out + rb) = ub;
        *(uint4*)((char*)outd + rb) = ud;
    }
}

// ---------------- final divide: per-graph count via binary search on sorted gid ----------------

__global__ __launch_bounds__(256) void k_div(float* __restrict__ out, const float* __restrict__ pout,
                                             const int* __restrict__ gid, int N, int total) {
    int i = blockIdx.x * blockDim.x + threadIdx.x;
    if (i >= total) return;
    int g = i >> 6;
    int lo = 0, hi = N;
    while (lo < hi) { int m = (lo + hi) >> 1; if (gid[m] < g) lo = m + 1; else hi = m; }
    int s = lo;
    hi = N;
    while (lo < hi) { int m = (lo + hi) >> 1; if (gid[m] < g + 1) lo = m + 1; else hi = m; }
    float c = (float)(lo - s);
    out[i] = pout[i] / fmaxf(c, 1.f);
}

// ---------------- launcher ----------------

extern "C" void kernel_launch(void* const* d_in, const int* in_sizes, int n_in,
                              void* d_out, int out_size, void* d_ws, size_t ws_size,
                              hipStream_t stream) {
    const float* feat = (const float*)d_in[0];
    const int* src = (const int*)d_in[1];
    const int* dst = (const int*)d_in[2];
    const int* gid = (const int*)d_in[3];
    const float* W1 = (const float*)d_in[4];  const float* b1 = (const float*)d_in[5];
    const float* W2 = (const float*)d_in[6];  const float* b2 = (const float*)d_in[7];
    const float* W3 = (const float*)d_in[8];  const float* b3 = (const float*)d_in[9];
    const float* Wt1 = (const float*)d_in[10]; const float* bt1 = (const float*)d_in[11];
    const float* Wp1 = (const float*)d_in[12]; const float* bp1 = (const float*)d_in[13];
    const float* Wt2 = (const float*)d_in[14]; const float* bt2 = (const float*)d_in[15];
    const float* Wp2 = (const float*)d_in[16]; const float* bp2 = (const float*)d_in[17];
    float* out = (float*)d_out;

    const int N = in_sizes[0] / 16;
    const int E = in_sizes[1];
    const int G = out_size / 64;
    const int nb = (N + 255) >> 8;      // buckets (<= 512)

    char* p = (char*)d_ws;
    auto alloc = [&](size_t nbytes) {
        void* r = (void*)p;
        p += (nbytes + 255) & ~(size_t)255;
        return r;
    };
    // zero-block: bcur | zpage | pout contiguous -> single memset
    int* bcur     = (int*)alloc(512 * 4);
    char* zpage   = (char*)alloc(256);
    float* pout   = (float*)alloc((size_t)G * 64 * 4);
    size_t zspan  = (size_t)((char*)pout - (char*)bcur) + (((size_t)G * 64 * 4 + 255) & ~(size_t)255);
    int2* row_be  = (int2*)alloc((size_t)N * 8);
    int* csr      = (int*)alloc(((size_t)nb * SLABC + 1024) * 4);
    float* dinv   = (float*)alloc((size_t)N * 4);
    float* dsq    = (float*)alloc((size_t)N * 4);
    size_t slabBytes = (size_t)nb * SLABC * 4;
    size_t xd3Bytes  = (size_t)N * 64 * 2;
    float* bufA   = (float*)alloc(slabBytes > xd3Bytes ? slabBytes : xd3Bytes);  // ebuf slab / xA16 / xd3 (BUGFIX R8: must hold xd3's 12.8MB)
    float* bufB   = (float*)alloc((size_t)N * 64 * 2);       // X2 bf16
    float* bufC   = (float*)alloc((size_t)N * 64 * 4);       // hd | xd (bf16 halves)
    unsigned short* hD   = (unsigned short*)alloc((size_t)N * 64 * 2);
    unsigned short* md   = (unsigned short*)alloc((size_t)N * 64 * 2);
    unsigned short* pbuf = (unsigned short*)alloc((size_t)N * 64 * 2);

    unsigned* ebuf = (unsigned*)bufA;                    // slab: nb*SLABC entries
    unsigned short* hd = (unsigned short*)bufC;          // dinv-scaled h (gather operand)
    unsigned short* xd = hd + (size_t)N * 64;            // dinv-scaled X1 (layers 1,2)
    unsigned short* xA16 = (unsigned short*)bufA;        // layer-1 X1 bf16 (ebuf dead after finish)
    unsigned short* xd3 = (unsigned short*)bufA;         // layer-3 dinv-scaled X1
    unsigned short* xB16 = (unsigned short*)bufB;        // X2 bf16 (all layers)

    const int zo_hd = (int)((char*)zpage - (char*)hd);
    const int zo_xd = (int)((char*)zpage - (char*)xd);
    const int zo_xd3 = (int)((char*)zpage - (char*)xd3);
    const int zo_md = (int)((char*)zpage - (char*)md);

    hipMemsetAsync(bcur, 0, zspan, stream);

    const int nbw = (N + 3) / 4;
    const int nbt = (N + 63) / 64;
    const int npart = (E + PCHUNK - 1) / PCHUNK;

    // ---- slab-bucket CSR build (2 launches; k_finish fuses feat->bf16 prescale)
    k_partA<<<npart, 256, 0, stream>>>(src, dst, bcur, ebuf, E);
    k_finish<<<nb, 256, 0, stream>>>(ebuf, bcur, row_be, dinv, dsq, csr, feat, hd, N);

    // ---- Cheb layer 1 (IN=16) + EdgeConv1 stage 1 (fused)
    k_aggr16<<<nbw, 256, 0, stream>>>(hd, nullptr, dinv, row_be, csr, xA16, xd, -1.f, 0.f, zo_hd, N);
    k_aggr16<<<nbw, 256, 0, stream>>>(xd, feat, dinv, row_be, csr, xB16, nullptr, -2.f, -1.f, zo_xd, N);
    k_cheb<16, true, false><<<nbt, 256, 0, stream>>>(feat, xA16, xB16, nullptr, W1, b1,
                                                     Wt1, Wp1, bt1, bp1, md, pbuf, nullptr, nullptr, N);
    k_e2_b<<<nbw, 256, 0, stream>>>(md, pbuf, row_be, csr, dinv, hD, hd, zo_md, N);

    // ---- Cheb layer 2 + EdgeConv2 stage 1 (fused)
    k_aggr64<<<nbw, 256, 0, stream>>>(hd, nullptr, dinv, row_be, csr, nullptr, xd, -1.f, 0.f, zo_hd, N);
    k_aggr64<<<nbw, 256, 0, stream>>>(xd, hD, dinv, row_be, csr, xB16, nullptr, -2.f, -1.f, zo_xd, N);
    k_cheb<64, true, false><<<nbt, 256, 0, stream>>>(hD, xd, xB16, dsq, W2, b2,
                                                     Wt2, Wp2, bt2, bp2, md, pbuf, nullptr, nullptr, N);
    k_e2_b<<<nbw, 256, 0, stream>>>(md, pbuf, row_be, csr, dinv, hD, hd, zo_md, N);

    // ---- Cheb layer 3 with fused atomic mean-pool (xd3 in bufA: no alias with hd)
    k_aggr64<<<nbw, 256, 0, stream>>>(hd, nullptr, dinv, row_be, csr, nullptr, xd3, -1.f, 0.f, zo_hd, N);
    k_aggr64<<<nbw, 256, 0, stream>>>(xd3, hD, dinv, row_be, csr, xB16, nullptr, -2.f, -1.f, zo_xd3, N);
    k_cheb<64, false, true><<<nbt, 256, 0, stream>>>(hD, xd3, xB16, dsq, W3, b3,
                                                     nullptr, nullptr, nullptr, nullptr,
                                                     nullptr, nullptr, gid, pout, N);

    // ---- divide by per-graph counts (binary search on sorted gid)
    k_div<<<(out_size + 255) / 256, 256, 0, stream>>>(out, pout, gid, N, out_size);
}